// Round 4
// baseline (275.483 us; speedup 1.0000x reference)
//
#include <hip/hip_runtime.h>
#include <math.h>

#define L 2048
#define LMASK (L - 1)
#define LB 512            // int4-blocks per row
#define LBMASK (LB - 1)
#define NCELL (L * L)
#define H 64
#define BLK 256

#define RED_BLOCKS 1024
#define RED_ITERS (NCELL / 4 / (RED_BLOCKS * BLK))   // 4

// ---------------- Kernel 1: per-block partial sums (NO atomics) ----------------
__global__ void reduce_sum_kernel(const int* __restrict__ state,
                                  int* __restrict__ partials) {
    const int4* s4 = (const int4*)state;
    int tid = blockIdx.x * blockDim.x + threadIdx.x;
    int x = 0;
    #pragma unroll
    for (int k = 0; k < RED_ITERS; ++k) {
        int4 v = s4[tid + k * (RED_BLOCKS * BLK)];
        x += v.x + v.y + v.z + v.w;
    }
    #pragma unroll
    for (int off = 32; off > 0; off >>= 1)
        x += __shfl_down(x, off, 64);
    __shared__ int ls[4];
    if ((threadIdx.x & 63) == 0) ls[threadIdx.x >> 6] = x;
    __syncthreads();
    if (threadIdx.x == 0)
        partials[blockIdx.x] = ls[0] + ls[1] + ls[2] + ls[3];
}

// ---------------- Kernel 2: per-block MLP table + stencil + store ----------------
// reward = 3*(n+s+e+w) + 2*(ne+nw+se+sw) + (nn+ss+ee+ww)   [center cancels, R=5]
__global__ __launch_bounds__(BLK)
void cell_kernel(const int* __restrict__ state,
                 const float* __restrict__ W1, const float* __restrict__ b1,
                 const float* __restrict__ W2, const float* __restrict__ b2,
                 const float* __restrict__ Wa, const float* __restrict__ ba,
                 const float* __restrict__ Wc, const float* __restrict__ bc,
                 const int* __restrict__ partials,
                 float* __restrict__ out) {
    __shared__ float tbl[48];
    __shared__ float h1s[12][H];
    __shared__ float h2s[12][H];
    __shared__ int   ls[4];
    __shared__ float gc_s;

    const int t = threadIdx.x;

    // --- reduce the 1024 partials (every block, redundant, L2-hit) ---
    int s = partials[t] + partials[t + 256] + partials[t + 512] + partials[t + 768];
    #pragma unroll
    for (int off = 32; off > 0; off >>= 1) s += __shfl_down(s, off, 64);
    if ((t & 63) == 0) ls[t >> 6] = s;
    __syncthreads();
    if (t == 0) gc_s = (float)(ls[0] + ls[1] + ls[2] + ls[3]) * (1.0f / (float)NCELL);
    __syncthreads();
    const float gc = gc_s;

    // --- 12-combo MLP table in LDS ---
    const int cb = t >> 4;          // combo 0..15 (12 active)
    const int kk = t & 15;          // 16 threads per combo, 4 hidden dims each
    if (cb < 12) {
        float f0 = (float)(cb / 6), f1 = (float)(cb % 6);
        #pragma unroll
        for (int d = 0; d < 4; ++d) {
            int j = kk * 4 + d;
            float a = W1[j] * f0 + W1[H + j] * f1 + W1[2 * H + j] * gc + b1[j];
            h1s[cb][j] = fmaxf(a, 0.f);
        }
    }
    __syncthreads();
    if (cb < 12) {
        #pragma unroll
        for (int d = 0; d < 4; ++d) {
            int j = kk * 4 + d;
            float acc = b2[j];
            #pragma unroll 8
            for (int q = 0; q < H; ++q) acc += h1s[cb][q] * W2[q * H + j];
            h2s[cb][j] = fmaxf(acc, 0.f);
        }
    }
    __syncthreads();
    if (t < 12) {
        float la = ba[0], lb = ba[1], v = bc[0];
        #pragma unroll 8
        for (int q = 0; q < H; ++q) {
            la += h2s[t][q] * Wa[q * 2 + 0];
            lb += h2s[t][q] * Wa[q * 2 + 1];
            v  += h2s[t][q] * Wc[q];
        }
        float m = fmaxf(la, lb);
        float e0 = expf(la - m), e1 = expf(lb - m);
        float inv = 1.f / (e0 + e1);
        tbl[t * 4 + 0] = e0 * inv;
        tbl[t * 4 + 1] = e1 * inv;
        tbl[t * 4 + 2] = v;
    }
    __syncthreads();

    // --- stencil + lookup + store (one int4-group per thread) ---
    int tid = blockIdx.x * BLK + t;     // 0 .. NCELL/4-1
    int i  = tid >> 9;                  // row
    int jb = tid & LBMASK;              // int4-block in row
    int im1 = (i - 1) & LMASK, ip1 = (i + 1) & LMASK;
    int im2 = (i - 2) & LMASK, ip2 = (i + 2) & LMASK;
    int jbm1 = (jb - 1) & LBMASK, jbp1 = (jb + 1) & LBMASK;

    const int4* s4 = (const int4*)state;
    int4 m0 = s4[i   * LB + jbm1], m1 = s4[i   * LB + jb], m2 = s4[i   * LB + jbp1];
    int4 n0 = s4[im1 * LB + jbm1], n1 = s4[im1 * LB + jb], n2 = s4[im1 * LB + jbp1];
    int4 q0 = s4[ip1 * LB + jbm1], q1 = s4[ip1 * LB + jb], q2 = s4[ip1 * LB + jbp1];
    int4 uu4 = s4[im2 * LB + jb];
    int4 dd4 = s4[ip2 * LB + jb];

    int m [12] = {m0.x,m0.y,m0.z,m0.w, m1.x,m1.y,m1.z,m1.w, m2.x,m2.y,m2.z,m2.w};
    int nr[12] = {n0.x,n0.y,n0.z,n0.w, n1.x,n1.y,n1.z,n1.w, n2.x,n2.y,n2.z,n2.w};
    int sr[12] = {q0.x,q0.y,q0.z,q0.w, q1.x,q1.y,q1.z,q1.w, q2.x,q2.y,q2.z,q2.w};
    int ur[4]  = {uu4.x,uu4.y,uu4.z,uu4.w};
    int dr[4]  = {dd4.x,dd4.y,dd4.z,dd4.w};

    float pr[8], vv[4], rw[4];
    #pragma unroll
    for (int u = 0; u < 4; ++u) {
        int c  = m[4 + u],  w  = m[3 + u],  e  = m[5 + u];
        int ww = m[2 + u],  ee = m[6 + u];
        int n  = nr[4 + u], nw = nr[3 + u], ne = nr[5 + u];
        int ss1 = sr[4 + u], sw = sr[3 + u], se = sr[5 + u];
        int nn = ur[u],     ssd = dr[u];

        int axis1 = n + ss1 + e + w;
        rw[u] = (float)(3 * axis1 + 2 * (nw + ne + sw + se) + (nn + ssd + ww + ee));

        int combo = c * 6 + (c + axis1);
        pr[2 * u]     = tbl[combo * 4 + 0];
        pr[2 * u + 1] = tbl[combo * 4 + 1];
        vv[u]         = tbl[combo * 4 + 2];
    }

    float4* o4 = (float4*)out;
    o4[(size_t)tid * 2]     = make_float4(pr[0], pr[1], pr[2], pr[3]);
    o4[(size_t)tid * 2 + 1] = make_float4(pr[4], pr[5], pr[6], pr[7]);
    ((float4*)(out + 2 * (size_t)NCELL))[tid] = make_float4(vv[0], vv[1], vv[2], vv[3]);
    ((float4*)(out + 3 * (size_t)NCELL))[tid] = make_float4(rw[0], rw[1], rw[2], rw[3]);
}

extern "C" void kernel_launch(void* const* d_in, const int* in_sizes, int n_in,
                              void* d_out, int out_size, void* d_ws, size_t ws_size,
                              hipStream_t stream) {
    const int*   state = (const int*)d_in[0];
    const float* W1 = (const float*)d_in[1];
    const float* b1 = (const float*)d_in[2];
    const float* W2 = (const float*)d_in[3];
    const float* b2 = (const float*)d_in[4];
    const float* Wa = (const float*)d_in[5];
    const float* ba = (const float*)d_in[6];
    const float* Wc = (const float*)d_in[7];
    const float* bc = (const float*)d_in[8];
    float* out = (float*)d_out;

    int* partials = (int*)d_ws;     // 1024 ints

    reduce_sum_kernel<<<RED_BLOCKS, BLK, 0, stream>>>(state, partials);
    cell_kernel<<<NCELL / 4 / BLK, BLK, 0, stream>>>(state, W1, b1, W2, b2,
                                                     Wa, ba, Wc, bc,
                                                     partials, out);
}

// Round 6
// 119.563 us; speedup vs baseline: 2.3041x; 2.3041x over previous
//
#include <hip/hip_runtime.h>
#include <math.h>

#define L 2048
#define LMASK (L - 1)
#define LB 512            // int4-blocks per row
#define LBMASK (LB - 1)
#define NCELL (L * L)
#define H 64
#define BLK 256

#define RED_BLOCKS 1024
#define RED_ITERS (NCELL / 4 / (RED_BLOCKS * BLK))   // 4

typedef float vfloat4 __attribute__((ext_vector_type(4)));  // clang-native for nontemporal

// ---------------- Kernel 1: per-block partial sums (NO atomics) ----------------
__global__ void reduce_sum_kernel(const int* __restrict__ state,
                                  int* __restrict__ partials) {
    const int4* s4 = (const int4*)state;
    int tid = blockIdx.x * blockDim.x + threadIdx.x;
    int x = 0;
    #pragma unroll
    for (int k = 0; k < RED_ITERS; ++k) {
        int4 v = s4[tid + k * (RED_BLOCKS * BLK)];
        x += v.x + v.y + v.z + v.w;
    }
    #pragma unroll
    for (int off = 32; off > 0; off >>= 1)
        x += __shfl_down(x, off, 64);
    __shared__ int ls[4];
    if ((threadIdx.x & 63) == 0) ls[threadIdx.x >> 6] = x;
    __syncthreads();
    if (threadIdx.x == 0)
        partials[blockIdx.x] = ls[0] + ls[1] + ls[2] + ls[3];
}

// ---------------- Kernel 2: 12-combo MLP table (12 blocks x 64 thr) ------------
// table[b*4 + {0,1,2}] = {p0, p1, value} for combo b = s*6 + nc
__global__ void mlp_table_kernel(const float* __restrict__ W1,
                                 const float* __restrict__ b1,
                                 const float* __restrict__ W2,
                                 const float* __restrict__ b2,
                                 const float* __restrict__ Wa,
                                 const float* __restrict__ ba,
                                 const float* __restrict__ Wc,
                                 const float* __restrict__ bc,
                                 const int* __restrict__ partials,
                                 float* __restrict__ table) {
    __shared__ float h1[H];
    __shared__ float h2[H];
    int b = blockIdx.x;                     // 0..11
    int j = threadIdx.x;                    // 0..63

    // reduce the 1024 partials (each block redundantly; one wave, L2-hit)
    int sum = 0;
    #pragma unroll
    for (int k = 0; k < RED_BLOCKS / 64; ++k)
        sum += partials[k * 64 + j];
    #pragma unroll
    for (int off = 32; off > 0; off >>= 1)
        sum += __shfl_xor(sum, off, 64);

    float f0 = (float)(b / 6);              // state
    float f1 = (float)(b % 6);              // neighbor_coop
    float f2 = (float)sum * (1.0f / (float)NCELL);  // global_coop

    float a = W1[0 * H + j] * f0 + W1[1 * H + j] * f1 + W1[2 * H + j] * f2 + b1[j];
    h1[j] = fmaxf(a, 0.0f);
    __syncthreads();

    float acc = b2[j];
    #pragma unroll
    for (int k = 0; k < H; ++k) acc += h1[k] * W2[k * H + j];
    h2[j] = fmaxf(acc, 0.0f);
    __syncthreads();

    if (j == 0) {
        float la = ba[0], lb = ba[1], v = bc[0];
        #pragma unroll
        for (int k = 0; k < H; ++k) {
            la += h2[k] * Wa[k * 2 + 0];
            lb += h2[k] * Wa[k * 2 + 1];
            v  += h2[k] * Wc[k];
        }
        float m = fmaxf(la, lb);
        float e0 = expf(la - m), e1 = expf(lb - m);
        float inv = 1.0f / (e0 + e1);
        table[b * 4 + 0] = e0 * inv;
        table[b * 4 + 1] = e1 * inv;
        table[b * 4 + 2] = v;
    }
}

// ---------------- Kernel 3: stencil + lookup + store ----------------
// reward = 3*(n+s+e+w) + 2*(ne+nw+se+sw) + (nn+ss+ee+ww)   [center cancels, R=5]
#define NXCD 8
#define GRID3 (NCELL / 4 / BLK)       // 4096 blocks
__global__ __launch_bounds__(BLK)
void cell_kernel(const int* __restrict__ state,
                 const float* __restrict__ table,
                 float* __restrict__ out) {
    __shared__ float tbl[48];
    if (threadIdx.x < 48) tbl[threadIdx.x] = table[threadIdx.x];
    __syncthreads();

    // XCD-contiguous swizzle: blocks land on XCD (blockIdx % 8); give each XCD
    // a contiguous 256-row slab so neighbor-row re-reads stay in its own L2.
    int blk = (blockIdx.x & (NXCD - 1)) * (GRID3 / NXCD) + (blockIdx.x >> 3);

    int tid = blk * BLK + threadIdx.x;  // 0 .. NCELL/4-1
    int i  = tid >> 9;                  // row
    int jb = tid & LBMASK;              // int4-block in row
    int im1 = (i - 1) & LMASK, ip1 = (i + 1) & LMASK;
    int im2 = (i - 2) & LMASK, ip2 = (i + 2) & LMASK;
    int jbm1 = (jb - 1) & LBMASK, jbp1 = (jb + 1) & LBMASK;

    const int4* s4 = (const int4*)state;
    int4 m0 = s4[i   * LB + jbm1], m1 = s4[i   * LB + jb], m2 = s4[i   * LB + jbp1];
    int4 n0 = s4[im1 * LB + jbm1], n1 = s4[im1 * LB + jb], n2 = s4[im1 * LB + jbp1];
    int4 q0 = s4[ip1 * LB + jbm1], q1 = s4[ip1 * LB + jb], q2 = s4[ip1 * LB + jbp1];
    int4 uu4 = s4[im2 * LB + jb];
    int4 dd4 = s4[ip2 * LB + jb];

    int m [12] = {m0.x,m0.y,m0.z,m0.w, m1.x,m1.y,m1.z,m1.w, m2.x,m2.y,m2.z,m2.w};
    int nr[12] = {n0.x,n0.y,n0.z,n0.w, n1.x,n1.y,n1.z,n1.w, n2.x,n2.y,n2.z,n2.w};
    int sr[12] = {q0.x,q0.y,q0.z,q0.w, q1.x,q1.y,q1.z,q1.w, q2.x,q2.y,q2.z,q2.w};
    int ur[4]  = {uu4.x,uu4.y,uu4.z,uu4.w};
    int dr[4]  = {dd4.x,dd4.y,dd4.z,dd4.w};

    float pr[8], vv[4], rw[4];
    #pragma unroll
    for (int u = 0; u < 4; ++u) {
        int c  = m[4 + u],  w  = m[3 + u],  e  = m[5 + u];
        int ww = m[2 + u],  ee = m[6 + u];
        int n  = nr[4 + u], nw = nr[3 + u], ne = nr[5 + u];
        int s  = sr[4 + u], sw = sr[3 + u], se = sr[5 + u];
        int nn = ur[u],     ss = dr[u];

        int axis1 = n + s + e + w;
        rw[u] = (float)(3 * axis1 + 2 * (nw + ne + sw + se) + (nn + ss + ww + ee));

        int combo = c * 6 + (c + axis1);
        pr[2 * u]     = tbl[combo * 4 + 0];
        pr[2 * u + 1] = tbl[combo * 4 + 1];
        vv[u]         = tbl[combo * 4 + 2];
    }

    // outputs are never re-read: nontemporal stores keep L2 for `state`
    vfloat4* o4 = (vfloat4*)out;
    vfloat4 s0 = {pr[0], pr[1], pr[2], pr[3]};
    vfloat4 s1 = {pr[4], pr[5], pr[6], pr[7]};
    vfloat4 s2 = {vv[0], vv[1], vv[2], vv[3]};
    vfloat4 s3 = {rw[0], rw[1], rw[2], rw[3]};
    __builtin_nontemporal_store(s0, &o4[(size_t)tid * 2]);
    __builtin_nontemporal_store(s1, &o4[(size_t)tid * 2 + 1]);
    __builtin_nontemporal_store(s2, &((vfloat4*)(out + 2 * (size_t)NCELL))[tid]);
    __builtin_nontemporal_store(s3, &((vfloat4*)(out + 3 * (size_t)NCELL))[tid]);
}

extern "C" void kernel_launch(void* const* d_in, const int* in_sizes, int n_in,
                              void* d_out, int out_size, void* d_ws, size_t ws_size,
                              hipStream_t stream) {
    const int*   state = (const int*)d_in[0];
    const float* W1 = (const float*)d_in[1];
    const float* b1 = (const float*)d_in[2];
    const float* W2 = (const float*)d_in[3];
    const float* b2 = (const float*)d_in[4];
    const float* Wa = (const float*)d_in[5];
    const float* ba = (const float*)d_in[6];
    const float* Wc = (const float*)d_in[7];
    const float* bc = (const float*)d_in[8];
    float* out = (float*)d_out;

    int*   partials = (int*)d_ws;                       // 1024 ints
    float* table    = (float*)((char*)d_ws + 8192);     // 48 floats

    reduce_sum_kernel<<<RED_BLOCKS, BLK, 0, stream>>>(state, partials);
    mlp_table_kernel<<<12, 64, 0, stream>>>(W1, b1, W2, b2, Wa, ba, Wc, bc,
                                            partials, table);
    cell_kernel<<<GRID3, BLK, 0, stream>>>(state, table, out);
}